// Round 1
// baseline (367.233 us; speedup 1.0000x reference)
//
#include <hip/hip_runtime.h>
#include <stdint.h>

#define CI 512
#define CO 512
#define HI 64
#define WI 64
#define HY 65
#define NB 8

typedef __bf16 bf16x8 __attribute__((ext_vector_type(8)));
typedef float f32x4 __attribute__((ext_vector_type(4)));

__device__ __forceinline__ unsigned short f2bf(float f) {
  unsigned int u = __float_as_uint(f);
  return (unsigned short)((u + 0x7fffu + ((u >> 16) & 1u)) >> 16);
}

// ---------------- Kernel A: FIR prefilter ----------------
// x: [8][512][64][64] f32  ->  yt: [8][65][65][512] bf16 (channel-last)
// y[r][s] = (1/64) * sum_{i,j} k1[i]*k1[j] * x[r-2+i][s-2+j], k1 = (1,3,3,1)
__global__ __launch_bounds__(256) void fir_kernel(const float* __restrict__ x,
                                                  unsigned short* __restrict__ yt) {
  const int gid = blockIdx.x * 256 + threadIdx.x;
  const int c = gid & (CI - 1);
  const int rest = gid >> 9;
  const int s = rest % HY;
  const int n = rest / HY;
  const float* xb = x + ((size_t)n * CI + c) * (HI * WI);

  const int c0 = s - 2, c1 = s - 1, c2 = s, c3 = s + 1;
  const bool v0 = (c0 >= 0);
  const bool v1 = (c1 >= 0);
  const bool v2 = (c2 < WI);
  const bool v3 = (c3 < WI);

  auto rowf = [&](int xr) -> float {
    if ((unsigned)xr >= (unsigned)HI) return 0.f;
    const float* row = xb + xr * WI;
    float a = 0.f;
    if (v0) a += row[c0];
    if (v1) a += 3.f * row[c1];
    if (v2) a += 3.f * row[c2];
    if (v3) a += row[c3];
    return a;
  };

  float h0 = 0.f, h1 = 0.f, h2 = rowf(0), h3 = rowf(1);
  unsigned short* yo = yt + ((size_t)n * HY * HY + s) * CI + c;
  for (int r = 0; r < HY; r++) {
    float y = (h0 + 3.f * h1 + 3.f * h2 + h3) * (1.f / 64.f);
    yo[(size_t)r * HY * CI] = f2bf(y);
    h0 = h1; h1 = h2; h2 = h3;
    h3 = rowf(r + 2);
  }
}

// ---------------- Kernel B: weight transform ----------------
// w: [512][512][3][3] f32 -> wtb: [9][co=512][ci=512] bf16 (ci contiguous)
__global__ __launch_bounds__(256) void wt_kernel(const float* __restrict__ w,
                                                 unsigned short* __restrict__ wtb) {
  const int gid = blockIdx.x * 256 + threadIdx.x;
  const int ci = gid & (CI - 1);
  const int co = gid >> 9;
  const float* src = w + ((size_t)co * CI + ci) * 9;
#pragma unroll
  for (int t = 0; t < 9; t++) {
    wtb[((size_t)t * CO + co) * CI + ci] = f2bf(src[t]);
  }
}

// ---------------- Kernel C: implicit-GEMM conv ----------------
// out[n][co][ho][wo] = bias[co] + sum_{tap,ci} W[co][ci][tap] * y[n][2ho+kh][2wo+kw][ci]
// Tile: 64 co x 128 pos, k-step 32 ci, 144 k-steps (9 taps x 16 ci-blocks).
// MFMA 16x16x32 bf16: A = W (i=co, k=ci), B = Y (k=ci, j=pos).
__global__ __launch_bounds__(256) void conv_kernel(
    const unsigned short* __restrict__ wtb,
    const unsigned short* __restrict__ yt,
    const float* __restrict__ bias,
    float* __restrict__ out) {
  __shared__ unsigned short Alds[64 * 32];
  __shared__ unsigned short Blds[128 * 32];

  const int tid = threadIdx.x;
  const int bid = blockIdx.x;
  const int co_t = (bid & 7) << 6;   // 8 co-tiles of 64
  const int m0 = (bid >> 3) << 7;    // 64 pos-tiles of 128
  const int n = m0 >> 10;
  const int ho_t = (m0 & 1023) >> 5; // tile covers ho_t..ho_t+3, wo 0..31

  // staging mapping: flat 16B chunk f -> row f>>2, ci-offset (f&3)*8
  const int frow = tid >> 2;         // 0..63
  const int fci = (tid & 3) << 3;

  const size_t wbase = (size_t)(co_t + frow) * CI + fci;
  const int p0 = frow, p1 = 64 + frow;
  const size_t yb0 = (((size_t)n * HY + 2 * (ho_t + (p0 >> 5))) * HY + 2 * (p0 & 31)) * CI + fci;
  const size_t yb1 = (((size_t)n * HY + 2 * (ho_t + (p1 >> 5))) * HY + 2 * (p1 & 31)) * CI + fci;

  uint4 ra, rb0, rb1;
  auto LOADT = [&](int ks) {
    const int tap = ks >> 4;
    const int ci0 = (ks & 15) << 5;
    const int kh = tap / 3;
    const int kw = tap - kh * 3;
    const size_t koff = ((size_t)kh * HY + kw) * CI + ci0;
    ra = *(const uint4*)(wtb + (size_t)tap * CO * CI + ci0 + wbase);
    rb0 = *(const uint4*)(yt + yb0 + koff);
    rb1 = *(const uint4*)(yt + yb1 + koff);
  };

  const int l = tid & 63;
  const int wv = tid >> 6;
  const int wco = (wv >> 1) << 5;   // wave co offset: 0/32
  const int wpos = (wv & 1) << 6;   // wave pos offset: 0/64
  const int ll = l & 15;
  const int kg = l >> 4;

  const unsigned short* pA = &Alds[(wco + ll) * 32 + kg * 8];
  const unsigned short* pB = &Blds[(wpos + ll) * 32 + kg * 8];

  f32x4 acc[2][4] = {};

  LOADT(0);
  for (int ks = 0; ks < 144; ks++) {
    __syncthreads();
    *(uint4*)&Alds[tid << 3] = ra;
    *(uint4*)&Blds[tid << 3] = rb0;
    *(uint4*)&Blds[(256 + tid) << 3] = rb1;
    __syncthreads();
    if (ks < 143) LOADT(ks + 1);  // prefetch next tile under MFMA

    const bf16x8 a0 = *(const bf16x8*)(pA);
    const bf16x8 a1 = *(const bf16x8*)(pA + 16 * 32);
    const bf16x8 b0 = *(const bf16x8*)(pB);
    const bf16x8 b1 = *(const bf16x8*)(pB + 16 * 32);
    const bf16x8 b2 = *(const bf16x8*)(pB + 32 * 32);
    const bf16x8 b3 = *(const bf16x8*)(pB + 48 * 32);

    acc[0][0] = __builtin_amdgcn_mfma_f32_16x16x32_bf16(a0, b0, acc[0][0], 0, 0, 0);
    acc[0][1] = __builtin_amdgcn_mfma_f32_16x16x32_bf16(a0, b1, acc[0][1], 0, 0, 0);
    acc[0][2] = __builtin_amdgcn_mfma_f32_16x16x32_bf16(a0, b2, acc[0][2], 0, 0, 0);
    acc[0][3] = __builtin_amdgcn_mfma_f32_16x16x32_bf16(a0, b3, acc[0][3], 0, 0, 0);
    acc[1][0] = __builtin_amdgcn_mfma_f32_16x16x32_bf16(a1, b0, acc[1][0], 0, 0, 0);
    acc[1][1] = __builtin_amdgcn_mfma_f32_16x16x32_bf16(a1, b1, acc[1][1], 0, 0, 0);
    acc[1][2] = __builtin_amdgcn_mfma_f32_16x16x32_bf16(a1, b2, acc[1][2], 0, 0, 0);
    acc[1][3] = __builtin_amdgcn_mfma_f32_16x16x32_bf16(a1, b3, acc[1][3], 0, 0, 0);
  }

  // Epilogue: D row=(lane>>4)*4+reg -> co-local; col=lane&15 -> pos-local (verified C/D layout)
#pragma unroll
  for (int i = 0; i < 2; i++) {
#pragma unroll
    for (int r = 0; r < 4; r++) {
      const int co = co_t + wco + i * 16 + kg * 4 + r;
      const float bv = bias[co];
#pragma unroll
      for (int j = 0; j < 4; j++) {
        const int pos = m0 + wpos + j * 16 + ll;
        const int ho = (pos & 1023) >> 5;
        const int wo = pos & 31;
        out[(((size_t)n * CO + co) * 32 + ho) * 32 + wo] = acc[i][j][r] + bv;
      }
    }
  }
}

extern "C" void kernel_launch(void* const* d_in, const int* in_sizes, int n_in,
                              void* d_out, int out_size, void* d_ws, size_t ws_size,
                              hipStream_t stream) {
  const float* x = (const float*)d_in[0];     // [8,512,64,64]
  const float* w = (const float*)d_in[1];     // [512,512,3,3]
  const float* bias = (const float*)d_in[2];  // [512]
  float* out = (float*)d_out;                 // [8,512,32,32]

  unsigned short* yt = (unsigned short*)d_ws;                    // 8*65*65*512 bf16
  unsigned short* wtb = yt + (size_t)NB * HY * HY * CI;          // 9*512*512 bf16

  fir_kernel<<<(NB * HY * CI) / 256, 256, 0, stream>>>(x, yt);   // 1040 blocks
  wt_kernel<<<(CO * CI) / 256, 256, 0, stream>>>(w, wtb);        // 1024 blocks
  conv_kernel<<<512, 256, 0, stream>>>(wtb, yt, bias, out);      // 512 blocks
}

// Round 2
// 124.399 us; speedup vs baseline: 2.9520x; 2.9520x over previous
//
#include <hip/hip_runtime.h>
#include <stdint.h>

#define CI 512
#define CO 512
#define HI 64
#define WI 64
#define HY 65
#define NB 8

typedef __bf16 bf16x8 __attribute__((ext_vector_type(8)));
typedef float f32x4 __attribute__((ext_vector_type(4)));

__device__ __forceinline__ unsigned short f2bf(float f) {
  unsigned int u = __float_as_uint(f);
  return (unsigned short)((u + 0x7fffu + ((u >> 16) & 1u)) >> 16);
}

// ---------------- Kernel A: FIR prefilter (LDS-tiled separable) ----------------
// x: [8][512][64][64] f32  ->  yt: [8][65][65][512] bf16 (channel-last)
// y[r][s] = (1/64) * (1,3,3,1)x(1,3,3,1) taps centered per upfirdn pad=(2,2)
#define CT 32   // channels per block
#define RT 13   // output rows per block (5 tiles cover 65)

__global__ __launch_bounds__(256) void fir_kernel(const float* __restrict__ x,
                                                  unsigned short* __restrict__ yt) {
  __shared__ float raw[CT][WI + 1];     // one image row per channel, pad col
  __shared__ float hrow[4][HY][CT];     // ring of horizontally-filtered rows

  const int tid = threadIdx.x;
  const int bid = blockIdx.x;
  const int n = bid / 80;
  const int rem = bid % 80;
  const int c0 = (rem / 5) * CT;
  const int r0 = (rem % 5) * RT;

  const float* xb = x + ((size_t)n * CI + c0) * (HI * WI);

  // staging map: 8 threads per channel-row, 2x float4 each
  const int lc = tid >> 3;  // 0..31
  const int lq = tid & 7;   // 0..7
  // compute map: lanes along c
  const int c = tid & (CT - 1);
  const int sb = tid >> 5;  // 0..7

  auto stage = [&](int hr) {
    __syncthreads();
    if ((unsigned)hr < (unsigned)HI) {
      const float* rowp = xb + ((size_t)lc * HI + hr) * WI;
      float4 a = *(const float4*)&rowp[lq * 4];
      float4 b = *(const float4*)&rowp[(lq + 8) * 4];
      raw[lc][lq * 4 + 0] = a.x; raw[lc][lq * 4 + 1] = a.y;
      raw[lc][lq * 4 + 2] = a.z; raw[lc][lq * 4 + 3] = a.w;
      raw[lc][(lq + 8) * 4 + 0] = b.x; raw[lc][(lq + 8) * 4 + 1] = b.y;
      raw[lc][(lq + 8) * 4 + 2] = b.z; raw[lc][(lq + 8) * 4 + 3] = b.w;
    }
    __syncthreads();
    const int slot = hr & 3;
    if ((unsigned)hr < (unsigned)HI) {
#pragma unroll
      for (int k = 0; k < 9; k++) {
        const int s = sb + (k << 3);
        if (s < HY) {
          float v = 0.f;
          if (s >= 2) v += raw[c][s - 2];
          if (s >= 1) v += 3.f * raw[c][s - 1];
          if (s <= 63) v += 3.f * raw[c][s];
          if (s <= 62) v += raw[c][s + 1];
          hrow[slot][s][c] = v;
        }
      }
    } else {
#pragma unroll
      for (int k = 0; k < 9; k++) {
        const int s = sb + (k << 3);
        if (s < HY) hrow[slot][s][c] = 0.f;
      }
    }
  };

  stage(r0 - 2);
  stage(r0 - 1);
  stage(r0);

  for (int i = 0; i < RT; i++) {
    const int r = r0 + i;
    stage(r + 1);
    __syncthreads();
    const int q0 = (r - 2) & 3, q1 = (r - 1) & 3, q2 = r & 3, q3 = (r + 1) & 3;
    unsigned short* yo = yt + (((size_t)n * HY + r) * HY) * CI + c0 + c;
#pragma unroll
    for (int k = 0; k < 9; k++) {
      const int s = sb + (k << 3);
      if (s < HY) {
        const float y = (hrow[q0][s][c] + 3.f * hrow[q1][s][c] +
                         3.f * hrow[q2][s][c] + hrow[q3][s][c]) * (1.f / 64.f);
        yo[(size_t)s * CI] = f2bf(y);
      }
    }
  }
}

// ---------------- Kernel B: weight transform ----------------
// w: [512][512][3][3] f32 -> wtb: [9][co=512][ci=512] bf16 (ci contiguous)
__global__ __launch_bounds__(256) void wt_kernel(const float* __restrict__ w,
                                                 unsigned short* __restrict__ wtb) {
  const int gid = blockIdx.x * 256 + threadIdx.x;
  const int ci = gid & (CI - 1);
  const int co = gid >> 9;
  const float* src = w + ((size_t)co * CI + ci) * 9;
#pragma unroll
  for (int t = 0; t < 9; t++) {
    wtb[((size_t)t * CO + co) * CI + ci] = f2bf(src[t]);
  }
}

// ---------------- Kernel C: implicit-GEMM conv ----------------
// out[n][co][ho][wo] = bias[co] + sum_{tap,ci} W[co][ci][tap] * y[n][2ho+kh][2wo+kw][ci]
// Tile: 64 co x 128 pos, k-step 32 ci, 144 k-steps (9 taps x 16 ci-blocks).
// MFMA 16x16x32 bf16: A = W (i=co, k=ci), B = Y (k=ci, j=pos).
__global__ __launch_bounds__(256) void conv_kernel(
    const unsigned short* __restrict__ wtb,
    const unsigned short* __restrict__ yt,
    const float* __restrict__ bias,
    float* __restrict__ out) {
  __shared__ unsigned short Alds[64 * 32];
  __shared__ unsigned short Blds[128 * 32];

  const int tid = threadIdx.x;
  const int bid = blockIdx.x;
  const int co_t = (bid & 7) << 6;   // 8 co-tiles of 64
  const int m0 = (bid >> 3) << 7;    // 64 pos-tiles of 128
  const int n = m0 >> 10;
  const int ho_t = (m0 & 1023) >> 5; // tile covers ho_t..ho_t+3, wo 0..31

  const int frow = tid >> 2;         // 0..63
  const int fci = (tid & 3) << 3;

  const size_t wbase = (size_t)(co_t + frow) * CI + fci;
  const int p0 = frow, p1 = 64 + frow;
  const size_t yb0 = (((size_t)n * HY + 2 * (ho_t + (p0 >> 5))) * HY + 2 * (p0 & 31)) * CI + fci;
  const size_t yb1 = (((size_t)n * HY + 2 * (ho_t + (p1 >> 5))) * HY + 2 * (p1 & 31)) * CI + fci;

  uint4 ra, rb0, rb1;
  auto LOADT = [&](int ks) {
    const int tap = ks >> 4;
    const int ci0 = (ks & 15) << 5;
    const int kh = tap / 3;
    const int kw = tap - kh * 3;
    const size_t koff = ((size_t)kh * HY + kw) * CI + ci0;
    ra = *(const uint4*)(wtb + (size_t)tap * CO * CI + ci0 + wbase);
    rb0 = *(const uint4*)(yt + yb0 + koff);
    rb1 = *(const uint4*)(yt + yb1 + koff);
  };

  const int l = tid & 63;
  const int wv = tid >> 6;
  const int wco = (wv >> 1) << 5;   // wave co offset: 0/32
  const int wpos = (wv & 1) << 6;   // wave pos offset: 0/64
  const int ll = l & 15;
  const int kg = l >> 4;

  const unsigned short* pA = &Alds[(wco + ll) * 32 + kg * 8];
  const unsigned short* pB = &Blds[(wpos + ll) * 32 + kg * 8];

  f32x4 acc[2][4] = {};

  LOADT(0);
  for (int ks = 0; ks < 144; ks++) {
    __syncthreads();
    *(uint4*)&Alds[tid << 3] = ra;
    *(uint4*)&Blds[tid << 3] = rb0;
    *(uint4*)&Blds[(256 + tid) << 3] = rb1;
    __syncthreads();
    if (ks < 143) LOADT(ks + 1);  // prefetch next tile under MFMA

    const bf16x8 a0 = *(const bf16x8*)(pA);
    const bf16x8 a1 = *(const bf16x8*)(pA + 16 * 32);
    const bf16x8 b0 = *(const bf16x8*)(pB);
    const bf16x8 b1 = *(const bf16x8*)(pB + 16 * 32);
    const bf16x8 b2 = *(const bf16x8*)(pB + 32 * 32);
    const bf16x8 b3 = *(const bf16x8*)(pB + 48 * 32);

    acc[0][0] = __builtin_amdgcn_mfma_f32_16x16x32_bf16(a0, b0, acc[0][0], 0, 0, 0);
    acc[0][1] = __builtin_amdgcn_mfma_f32_16x16x32_bf16(a0, b1, acc[0][1], 0, 0, 0);
    acc[0][2] = __builtin_amdgcn_mfma_f32_16x16x32_bf16(a0, b2, acc[0][2], 0, 0, 0);
    acc[0][3] = __builtin_amdgcn_mfma_f32_16x16x32_bf16(a0, b3, acc[0][3], 0, 0, 0);
    acc[1][0] = __builtin_amdgcn_mfma_f32_16x16x32_bf16(a1, b0, acc[1][0], 0, 0, 0);
    acc[1][1] = __builtin_amdgcn_mfma_f32_16x16x32_bf16(a1, b1, acc[1][1], 0, 0, 0);
    acc[1][2] = __builtin_amdgcn_mfma_f32_16x16x32_bf16(a1, b2, acc[1][2], 0, 0, 0);
    acc[1][3] = __builtin_amdgcn_mfma_f32_16x16x32_bf16(a1, b3, acc[1][3], 0, 0, 0);
  }

#pragma unroll
  for (int i = 0; i < 2; i++) {
#pragma unroll
    for (int r = 0; r < 4; r++) {
      const int co = co_t + wco + i * 16 + kg * 4 + r;
      const float bv = bias[co];
#pragma unroll
      for (int j = 0; j < 4; j++) {
        const int pos = m0 + wpos + j * 16 + ll;
        const int ho = (pos & 1023) >> 5;
        const int wo = pos & 31;
        out[(((size_t)n * CO + co) * 32 + ho) * 32 + wo] = acc[i][j][r] + bv;
      }
    }
  }
}

extern "C" void kernel_launch(void* const* d_in, const int* in_sizes, int n_in,
                              void* d_out, int out_size, void* d_ws, size_t ws_size,
                              hipStream_t stream) {
  const float* x = (const float*)d_in[0];     // [8,512,64,64]
  const float* w = (const float*)d_in[1];     // [512,512,3,3]
  const float* bias = (const float*)d_in[2];  // [512]
  float* out = (float*)d_out;                 // [8,512,32,32]

  unsigned short* yt = (unsigned short*)d_ws;                    // 8*65*65*512 bf16
  unsigned short* wtb = yt + (size_t)NB * HY * HY * CI;          // 9*512*512 bf16

  fir_kernel<<<NB * (CI / CT) * 5, 256, 0, stream>>>(x, yt);     // 640 blocks
  wt_kernel<<<(CO * CI) / 256, 256, 0, stream>>>(w, wtb);        // 1024 blocks
  conv_kernel<<<512, 256, 0, stream>>>(wtb, yt, bias, out);      // 512 blocks
}

// Round 3
// 95.732 us; speedup vs baseline: 3.8361x; 1.2995x over previous
//
#include <hip/hip_runtime.h>
#include <stdint.h>

#define CI 512
#define CO 512
#define HI 64
#define WI 64
#define HY 65
#define NB 8

typedef __bf16 bf16x8 __attribute__((ext_vector_type(8)));
typedef float f32x4 __attribute__((ext_vector_type(4)));

__device__ __forceinline__ unsigned short f2bf(float f) {
  unsigned int u = __float_as_uint(f);
  return (unsigned short)((u + 0x7fffu + ((u >> 16) & 1u)) >> 16);
}

// async global->LDS, 16B per lane. LDS dest must be base + lane*16 (linear).
__device__ __forceinline__ void async16(void* lds, const void* g) {
  __builtin_amdgcn_global_load_lds(
      (const __attribute__((address_space(1))) uint32_t*)g,
      (__attribute__((address_space(3))) uint32_t*)lds, 16, 0, 0);
}

// ---------------- Kernel A: FIR prefilter (LDS-tiled separable) ----------------
#define CT 32
#define RT 13

__global__ __launch_bounds__(256) void fir_kernel(const float* __restrict__ x,
                                                  unsigned short* __restrict__ yt) {
  __shared__ float raw[CT][WI + 1];
  __shared__ float hrow[4][HY][CT];

  const int tid = threadIdx.x;
  const int bid = blockIdx.x;
  const int n = bid / 80;
  const int rem = bid % 80;
  const int c0 = (rem / 5) * CT;
  const int r0 = (rem % 5) * RT;

  const float* xb = x + ((size_t)n * CI + c0) * (HI * WI);

  const int lc = tid >> 3;
  const int lq = tid & 7;
  const int c = tid & (CT - 1);
  const int sb = tid >> 5;

  auto stage = [&](int hr) {
    __syncthreads();
    if ((unsigned)hr < (unsigned)HI) {
      const float* rowp = xb + ((size_t)lc * HI + hr) * WI;
      float4 a = *(const float4*)&rowp[lq * 4];
      float4 b = *(const float4*)&rowp[(lq + 8) * 4];
      raw[lc][lq * 4 + 0] = a.x; raw[lc][lq * 4 + 1] = a.y;
      raw[lc][lq * 4 + 2] = a.z; raw[lc][lq * 4 + 3] = a.w;
      raw[lc][(lq + 8) * 4 + 0] = b.x; raw[lc][(lq + 8) * 4 + 1] = b.y;
      raw[lc][(lq + 8) * 4 + 2] = b.z; raw[lc][(lq + 8) * 4 + 3] = b.w;
    }
    __syncthreads();
    const int slot = hr & 3;
    if ((unsigned)hr < (unsigned)HI) {
#pragma unroll
      for (int k = 0; k < 9; k++) {
        const int s = sb + (k << 3);
        if (s < HY) {
          float v = 0.f;
          if (s >= 2) v += raw[c][s - 2];
          if (s >= 1) v += 3.f * raw[c][s - 1];
          if (s <= 63) v += 3.f * raw[c][s];
          if (s <= 62) v += raw[c][s + 1];
          hrow[slot][s][c] = v;
        }
      }
    } else {
#pragma unroll
      for (int k = 0; k < 9; k++) {
        const int s = sb + (k << 3);
        if (s < HY) hrow[slot][s][c] = 0.f;
      }
    }
  };

  stage(r0 - 2);
  stage(r0 - 1);
  stage(r0);

  for (int i = 0; i < RT; i++) {
    const int r = r0 + i;
    stage(r + 1);
    __syncthreads();
    const int q0 = (r - 2) & 3, q1 = (r - 1) & 3, q2 = r & 3, q3 = (r + 1) & 3;
    unsigned short* yo = yt + (((size_t)n * HY + r) * HY) * CI + c0 + c;
#pragma unroll
    for (int k = 0; k < 9; k++) {
      const int s = sb + (k << 3);
      if (s < HY) {
        const float y = (hrow[q0][s][c] + 3.f * hrow[q1][s][c] +
                         3.f * hrow[q2][s][c] + hrow[q3][s][c]) * (1.f / 64.f);
        yo[(size_t)s * CI] = f2bf(y);
      }
    }
  }
}

// ---------------- Kernel B: weight transform ----------------
__global__ __launch_bounds__(256) void wt_kernel(const float* __restrict__ w,
                                                 unsigned short* __restrict__ wtb) {
  const int gid = blockIdx.x * 256 + threadIdx.x;
  const int ci = gid & (CI - 1);
  const int co = gid >> 9;
  const float* src = w + ((size_t)co * CI + ci) * 9;
#pragma unroll
  for (int t = 0; t < 9; t++) {
    wtb[((size_t)t * CO + co) * CI + ci] = f2bf(src[t]);
  }
}

// ---------------- Kernel C: implicit-GEMM conv ----------------
// Tile: 64 co x 128 pos, BK=64 ci, 72 k-steps (9 taps x 8 ci-blocks).
// Double-buffered LDS, global_load_lds staging issued before compute,
// XOR slot swizzle (slot ^= row&7) on both source and ds_read.
__global__ __launch_bounds__(256, 2) void conv_kernel(
    const unsigned short* __restrict__ wtb,
    const unsigned short* __restrict__ yt,
    const float* __restrict__ bias,
    float* __restrict__ out) {
  __shared__ unsigned short Alds[2][64 * 64];    // 16 KB
  __shared__ unsigned short Blds[2][128 * 64];   // 32 KB

  const int tid = threadIdx.x;
  // XCD swizzle: 8 co-tiles sharing a pos-tile octet land on one XCD chunk
  const int wgid = ((blockIdx.x & 7) << 6) | (blockIdx.x >> 3);
  const int co_t = (wgid & 7) << 6;
  const int m0 = (wgid >> 3) << 7;
  const int n = m0 >> 10;
  const int w = tid >> 6, l = tid & 63;

  // ---- staging lane-invariant global offsets (swizzled source) ----
  size_t aoff[2];
#pragma unroll
  for (int i = 0; i < 2; i++) {
    const int cch = i * 256 + w * 64 + l;        // A chunk id 0..511
    const int row = cch >> 3, s = cch & 7;
    aoff[i] = (size_t)(co_t + row) * CI + ((s ^ (row & 7)) << 3);
  }
  size_t boff[4];
#pragma unroll
  for (int i = 0; i < 4; i++) {
    const int cch = i * 256 + w * 64 + l;        // B chunk id 0..1023
    const int p = cch >> 3, s = cch & 7;
    const int pos = m0 + p;
    const int ho = (pos & 1023) >> 5, wo = pos & 31;
    boff[i] = (((size_t)n * HY + 2 * ho) * HY + 2 * wo) * CI + ((s ^ (p & 7)) << 3);
  }

  auto stage = [&](int b, int ks) {
    const int tap = ks >> 3;
    const int ci0 = (ks & 7) << 6;
    const int kh = tap / 3, kw = tap - kh * 3;
    const size_t ka = (size_t)tap * (CO * CI) + ci0;
    const size_t kb = (size_t)(kh * HY + kw) * CI + ci0;
    unsigned short* Ab = &Alds[b][0];
    unsigned short* Bb = &Blds[b][0];
#pragma unroll
    for (int i = 0; i < 2; i++)
      async16(Ab + (size_t)(i * 256 + w * 64 + l) * 8, wtb + ka + aoff[i]);
#pragma unroll
    for (int i = 0; i < 4; i++)
      async16(Bb + (size_t)(i * 256 + w * 64 + l) * 8, yt + kb + boff[i]);
  };

  // ---- compute-side fragment addresses (swizzled read) ----
  const int wco = (w >> 1) << 5;   // 0 / 32
  const int wpos = (w & 1) << 6;   // 0 / 64
  const int ll = l & 15, kg = l >> 4;
  const int a7 = ll & 7;

  int aidx[2][2], bidx[4][2];
#pragma unroll
  for (int m = 0; m < 2; m++)
#pragma unroll
    for (int kk = 0; kk < 2; kk++)
      aidx[m][kk] = (wco + m * 16 + ll) * 64 + ((((kk << 2) | kg) ^ a7) << 3);
#pragma unroll
  for (int nf = 0; nf < 4; nf++)
#pragma unroll
    for (int kk = 0; kk < 2; kk++)
      bidx[nf][kk] = (wpos + nf * 16 + ll) * 64 + ((((kk << 2) | kg) ^ a7) << 3);

  f32x4 acc[2][4] = {};

  stage(0, 0);
  __syncthreads();

  int cur = 0;
  for (int ks = 0; ks < 72; ks++) {
    if (ks < 71) stage(cur ^ 1, ks + 1);   // loads in flight across compute
    const unsigned short* Ac = &Alds[cur][0];
    const unsigned short* Bc = &Blds[cur][0];
#pragma unroll
    for (int kk = 0; kk < 2; kk++) {
      const bf16x8 a0 = *(const bf16x8*)(Ac + aidx[0][kk]);
      const bf16x8 a1 = *(const bf16x8*)(Ac + aidx[1][kk]);
      const bf16x8 b0 = *(const bf16x8*)(Bc + bidx[0][kk]);
      const bf16x8 b1 = *(const bf16x8*)(Bc + bidx[1][kk]);
      const bf16x8 b2 = *(const bf16x8*)(Bc + bidx[2][kk]);
      const bf16x8 b3 = *(const bf16x8*)(Bc + bidx[3][kk]);
      acc[0][0] = __builtin_amdgcn_mfma_f32_16x16x32_bf16(a0, b0, acc[0][0], 0, 0, 0);
      acc[0][1] = __builtin_amdgcn_mfma_f32_16x16x32_bf16(a0, b1, acc[0][1], 0, 0, 0);
      acc[0][2] = __builtin_amdgcn_mfma_f32_16x16x32_bf16(a0, b2, acc[0][2], 0, 0, 0);
      acc[0][3] = __builtin_amdgcn_mfma_f32_16x16x32_bf16(a0, b3, acc[0][3], 0, 0, 0);
      acc[1][0] = __builtin_amdgcn_mfma_f32_16x16x32_bf16(a1, b0, acc[1][0], 0, 0, 0);
      acc[1][1] = __builtin_amdgcn_mfma_f32_16x16x32_bf16(a1, b1, acc[1][1], 0, 0, 0);
      acc[1][2] = __builtin_amdgcn_mfma_f32_16x16x32_bf16(a1, b2, acc[1][2], 0, 0, 0);
      acc[1][3] = __builtin_amdgcn_mfma_f32_16x16x32_bf16(a1, b3, acc[1][3], 0, 0, 0);
    }
    __syncthreads();   // drains vmcnt (next tile staged) + lgkm
    cur ^= 1;
  }

  // Epilogue: C/D row=(lane>>4)*4+reg -> co; col=lane&15 -> pos (verified layout)
#pragma unroll
  for (int i = 0; i < 2; i++) {
#pragma unroll
    for (int r = 0; r < 4; r++) {
      const int co = co_t + wco + i * 16 + kg * 4 + r;
      const float bv = bias[co];
#pragma unroll
      for (int j = 0; j < 4; j++) {
        const int pos = m0 + wpos + j * 16 + ll;
        const int ho = (pos & 1023) >> 5;
        const int wo = pos & 31;
        out[(((size_t)n * CO + co) * 32 + ho) * 32 + wo] = acc[i][j][r] + bv;
      }
    }
  }
}

extern "C" void kernel_launch(void* const* d_in, const int* in_sizes, int n_in,
                              void* d_out, int out_size, void* d_ws, size_t ws_size,
                              hipStream_t stream) {
  const float* x = (const float*)d_in[0];     // [8,512,64,64]
  const float* w = (const float*)d_in[1];     // [512,512,3,3]
  const float* bias = (const float*)d_in[2];  // [512]
  float* out = (float*)d_out;                 // [8,512,32,32]

  unsigned short* yt = (unsigned short*)d_ws;                    // 8*65*65*512 bf16
  unsigned short* wtb = yt + (size_t)NB * HY * HY * CI;          // 9*512*512 bf16

  fir_kernel<<<NB * (CI / CT) * 5, 256, 0, stream>>>(x, yt);     // 640 blocks
  wt_kernel<<<(CO * CI) / 256, 256, 0, stream>>>(w, wtb);        // 1024 blocks
  conv_kernel<<<512, 256, 0, stream>>>(wtb, yt, bias, out);      // 512 blocks
}